// Round 2
// 1752.493 us; speedup vs baseline: 1.5968x; 1.5968x over previous
//
#include <hip/hip_runtime.h>
#include <hip/hip_bf16.h>
#include <hip/hip_fp16.h>

// QuantizedLinear: out[M,N] = x[M,K] . W^T[N,K] + bias, W = (q - zero)*scale per group
// M=8192 (B*S), K=4096 (IN), N=11008 (OUT), 32 groups of 128 along K.
//
// Round 4 (= round 3 resubmit; round-3 bench died to a container infra flake):
// (a) dequant/convert pre-passes into workspace (x fp32->bf16 64MiB,
//     qweight int32->bf16 86MiB; both fit the 256MiB Infinity Cache), then
// (b) m97-structure bf16 GEMM: 128x128 tile, BK=32, global_load_lds width=16
//     for BOTH operands, 4 waves x 4x4 acc of mfma_f32_16x16x32_bf16.
// Rationale: round-2 kernel re-fetched 8.8 GB/dispatch (each tile re-reads
// full K-strips of the 180MB int32 qweight + 134MB fp32 x). Repacked operand
// set = 150MiB < L3 -> GEMM becomes compute-bound.

typedef __bf16 bf16x8 __attribute__((ext_vector_type(8)));
typedef __bf16 bf16x4 __attribute__((ext_vector_type(4)));
typedef float  floatx4 __attribute__((ext_vector_type(4)));

constexpr int Mdim = 8192;
constexpr int Kdim = 4096;
constexpr int Ndim = 11008;
constexpr int NG   = 32;    // groups per output row

__device__ __forceinline__ __bf16 f2b(float f) { return (__bf16)f; }  // fptrunc = RNE

// ---------------------------------------------------------------------------
// Pre-pass 1: x fp32 -> bf16 (grid-stride, float4 in / bf16x4 out)
// ---------------------------------------------------------------------------
__global__ __launch_bounds__(256)
void conv_x_kernel(const float* __restrict__ x, __bf16* __restrict__ xb)
{
    const size_t total4 = (size_t)Mdim * Kdim / 4;
    const size_t stride = (size_t)gridDim.x * blockDim.x;
    for (size_t i = (size_t)blockIdx.x * blockDim.x + threadIdx.x; i < total4; i += stride) {
        const float4 v = ((const float4*)x)[i];
        bf16x4 w;
        w[0] = f2b(v.x); w[1] = f2b(v.y); w[2] = f2b(v.z); w[3] = f2b(v.w);
        ((bf16x4*)xb)[i] = w;
    }
}

// ---------------------------------------------------------------------------
// Pre-pass 2: dequant int32 codes -> bf16 W[N,K]  (w = (q - zero)*scale)
// ---------------------------------------------------------------------------
__global__ __launch_bounds__(256)
void dequant_w_kernel(const int* __restrict__ qw, const float* __restrict__ scales,
                      const float* __restrict__ zeros, __bf16* __restrict__ wb)
{
    const size_t total4 = (size_t)Ndim * Kdim / 4;   // int4 chunks
    const size_t stride = (size_t)gridDim.x * blockDim.x;
    for (size_t i = (size_t)blockIdx.x * blockDim.x + threadIdx.x; i < total4; i += stride) {
        const int n  = (int)(i >> 10);        // / (Kdim/4 = 1024)
        const int k4 = (int)(i & 1023);
        const int g  = k4 >> 5;               // (k4*4) / 128
        const int4 q = ((const int4*)qw)[i];
        const float sf = scales[n * NG + g];
        const float zf = zeros [n * NG + g];
        bf16x4 w;
        w[0] = f2b(((float)q.x - zf) * sf);
        w[1] = f2b(((float)q.y - zf) * sf);
        w[2] = f2b(((float)q.z - zf) * sf);
        w[3] = f2b(((float)q.w - zf) * sf);
        ((bf16x4*)wb)[i] = w;
    }
}

// ---------------------------------------------------------------------------
// Main GEMM: m97 structure. A[M,K] bf16, B[N,K] bf16 (B^T form), out fp32+bias.
// ---------------------------------------------------------------------------
#define BM 128
#define BN 128
#define BK 32

typedef const __attribute__((address_space(1))) void* gptr_t;
typedef __attribute__((address_space(3))) void* lptr_t;

__global__ __launch_bounds__(256, 2)
void gemm_bf16(const __bf16* __restrict__ A, const __bf16* __restrict__ Bw,
               const float* __restrict__ bias, float* __restrict__ out)
{
    __shared__ __align__(16) __bf16 sA[BM * BK];   // 8 KB
    __shared__ __align__(16) __bf16 sB[BN * BK];   // 8 KB

    const int n0 = blockIdx.x * BN;
    const int m0 = blockIdx.y * BM;

    const int t    = threadIdx.x;
    const int lane = t & 63;
    const int wave = t >> 6;
    const int wr   = (wave >> 1) * 64;   // wave row origin in tile
    const int wc   = (wave & 1) * 64;    // wave col origin in tile
    const int quad = lane >> 4;
    const int l16  = lane & 15;

    // global_load_lds staging: one wave-issue = 64 lanes x 16B = 1024 B
    // = 16 rows x 64 B (BK=32 bf16). LDS dest is linear: base + lane*16,
    // which matches row = idx*16 + (lane>>2), kbyte = (lane&3)*16 exactly.
    const int srow  = lane >> 2;         // row within 16-row chunk
    const int skoff = (lane & 3) * 8;    // bf16 elem offset within row

    floatx4 acc[4][4] = {};

    const __bf16* Abase = A  + (size_t)m0 * Kdim;
    const __bf16* Bbase = Bw + (size_t)n0 * Kdim;

    for (int k0 = 0; k0 < Kdim; k0 += BK) {
        // ---- stage A & B via async global->LDS (width 16) ----
        #pragma unroll
        for (int p = 0; p < 2; ++p) {
            const int idx = wave * 2 + p;           // 0..7, wave-uniform
            const int row = idx * 16 + srow;
            __builtin_amdgcn_global_load_lds(
                (gptr_t)(Abase + (size_t)row * Kdim + k0 + skoff),
                (lptr_t)(sA + idx * 512), 16, 0, 0);
            __builtin_amdgcn_global_load_lds(
                (gptr_t)(Bbase + (size_t)row * Kdim + k0 + skoff),
                (lptr_t)(sB + idx * 512), 16, 0, 0);
        }
        __syncthreads();   // compiler inserts vmcnt(0) drain before barrier

        // ---- fragments + MFMA: each wave 4x4 of 16x16x32 ----
        bf16x8 af[4], bfr[4];
        #pragma unroll
        for (int i = 0; i < 4; ++i)
            af[i] = *(const bf16x8*)(&sA[(wr + i * 16 + l16) * BK + quad * 8]);
        #pragma unroll
        for (int j = 0; j < 4; ++j)
            bfr[j] = *(const bf16x8*)(&sB[(wc + j * 16 + l16) * BK + quad * 8]);

        #pragma unroll
        for (int i = 0; i < 4; ++i)
            #pragma unroll
            for (int j = 0; j < 4; ++j)
                acc[i][j] = __builtin_amdgcn_mfma_f32_16x16x32_bf16(
                                af[i], bfr[j], acc[i][j], 0, 0, 0);

        __syncthreads();
    }

    // ---- epilogue: C/D layout row=quad*4+r, col=l16; add bias, store fp32 ----
    float bj[4];
    #pragma unroll
    for (int j = 0; j < 4; ++j) bj[j] = bias[n0 + wc + j * 16 + l16];

    #pragma unroll
    for (int i = 0; i < 4; ++i) {
        const int m = m0 + wr + i * 16 + quad * 4;
        #pragma unroll
        for (int j = 0; j < 4; ++j) {
            const int n = n0 + wc + j * 16 + l16;
            float* o = out + (size_t)m * Ndim + n;
            #pragma unroll
            for (int r = 0; r < 4; ++r)
                o[(size_t)r * Ndim] = acc[i][j][r] + bj[j];
        }
    }
}

// ---------------------------------------------------------------------------
// Fallback (round-2 verified kernel) if workspace is too small.
// ---------------------------------------------------------------------------
__global__ __launch_bounds__(256, 2)
void qlinear_mfma(const float* __restrict__ x,
                  const int*   __restrict__ qw,
                  const float* __restrict__ scales,
                  const float* __restrict__ zeros,
                  const float* __restrict__ bias,
                  float* __restrict__ out)
{
    __shared__ __align__(16) __bf16 sA[BM * BK];
    __shared__ __align__(16) __bf16 sB[BN * BK];

    const int n0 = blockIdx.x * BN;
    const int m0 = blockIdx.y * BM;

    const int t    = threadIdx.x;
    const int lane = t & 63;
    const int wave = t >> 6;
    const int wr   = (wave >> 1) * 64;
    const int wc   = (wave & 1) * 64;
    const int quad = lane >> 4;
    const int l16  = lane & 15;

    const int sr = t >> 3;
    const int sc = (t & 7) * 4;

    floatx4 acc[4][4] = {};

    for (int k0 = 0; k0 < Kdim; k0 += BK) {
        const int g = k0 >> 7;

        #pragma unroll
        for (int p = 0; p < 4; ++p) {
            const int row = p * 32 + sr;
            const float4 v = *(const float4*)(x + (m0 + row) * Kdim + k0 + sc);
            bf16x4 w;
            w[0] = f2b(v.x); w[1] = f2b(v.y); w[2] = f2b(v.z); w[3] = f2b(v.w);
            *(bf16x4*)(&sA[row * BK + sc]) = w;
        }
        #pragma unroll
        for (int p = 0; p < 4; ++p) {
            const int row = p * 32 + sr;
            const int n   = n0 + row;
            const int4 q  = *(const int4*)(qw + n * Kdim + k0 + sc);
            const float sf = scales[n * NG + g];
            const float zf = zeros [n * NG + g];
            bf16x4 w;
            w[0] = f2b(((float)q.x - zf) * sf);
            w[1] = f2b(((float)q.y - zf) * sf);
            w[2] = f2b(((float)q.z - zf) * sf);
            w[3] = f2b(((float)q.w - zf) * sf);
            *(bf16x4*)(&sB[row * BK + sc]) = w;
        }
        __syncthreads();

        bf16x8 af[4], bfr[4];
        #pragma unroll
        for (int i = 0; i < 4; ++i)
            af[i] = *(bf16x8*)(&sA[(wr + i * 16 + l16) * BK + quad * 8]);
        #pragma unroll
        for (int j = 0; j < 4; ++j)
            bfr[j] = *(bf16x8*)(&sB[(wc + j * 16 + l16) * BK + quad * 8]);

        #pragma unroll
        for (int i = 0; i < 4; ++i)
            #pragma unroll
            for (int j = 0; j < 4; ++j)
                acc[i][j] = __builtin_amdgcn_mfma_f32_16x16x32_bf16(
                                af[i], bfr[j], acc[i][j], 0, 0, 0);

        __syncthreads();
    }

    float bj[4];
    #pragma unroll
    for (int j = 0; j < 4; ++j) bj[j] = bias[n0 + wc + j * 16 + l16];

    #pragma unroll
    for (int i = 0; i < 4; ++i) {
        const int m = m0 + wr + i * 16 + quad * 4;
        #pragma unroll
        for (int j = 0; j < 4; ++j) {
            const int n = n0 + wc + j * 16 + l16;
            float* o = out + (size_t)m * Ndim + n;
            #pragma unroll
            for (int r = 0; r < 4; ++r)
                o[(size_t)r * Ndim] = acc[i][j][r] + bj[j];
        }
    }
}

extern "C" void kernel_launch(void* const* d_in, const int* in_sizes, int n_in,
                              void* d_out, int out_size, void* d_ws, size_t ws_size,
                              hipStream_t stream) {
    const float* x      = (const float*)d_in[0];
    const int*   qwt    = (const int*)d_in[1];
    const float* scales = (const float*)d_in[2];
    const float* zeros  = (const float*)d_in[3];
    const float* bias   = (const float*)d_in[4];
    float* out = (float*)d_out;

    const size_t xb_bytes = (size_t)Mdim * Kdim * sizeof(__bf16);   // 64 MiB
    const size_t wb_bytes = (size_t)Ndim * Kdim * sizeof(__bf16);   // ~86 MiB
    const size_t needed   = xb_bytes + wb_bytes;                    // 150 MiB

    if (ws_size >= needed && d_ws != nullptr) {
        __bf16* xb = (__bf16*)d_ws;
        __bf16* wb = (__bf16*)((char*)d_ws + xb_bytes);

        conv_x_kernel  <<<2048, 256, 0, stream>>>(x, xb);
        dequant_w_kernel<<<2048, 256, 0, stream>>>(qwt, scales, zeros, wb);

        dim3 grid(Ndim / BN, Mdim / BM);   // 86 x 64 = 5504 blocks
        gemm_bf16<<<grid, 256, 0, stream>>>(xb, wb, bias, out);
    } else {
        dim3 grid(Ndim / BN, Mdim / BM);
        qlinear_mfma<<<grid, 256, 0, stream>>>(x, qwt, scales, zeros, bias, out);
    }
}

// Round 3
// 1744.458 us; speedup vs baseline: 1.6041x; 1.0046x over previous
//
#include <hip/hip_runtime.h>
#include <hip/hip_bf16.h>
#include <hip/hip_fp16.h>

// QuantizedLinear: out[M,N] = x[M,K] . W^T[N,K] + bias, W = (q - zero)*scale per group
// M=8192 (B*S), K=4096 (IN), N=11008 (OUT), 32 groups of 128 along K.
//
// Round 5: round-4 pre-pass+GEMM split, plus NONTEMPORAL output stores.
// Round-4 post-mortem: GEMM FETCH_SIZE 4.2GB at 3.74TB/s == dur exactly ->
// still HBM-bound. Operands (150MiB bf16) fit L3, but the 362MB output
// stream write-allocates through the memory-side Infinity Cache, cycling its
// 256MiB ~1.4x per dispatch and evicting the operands (-> 28x re-fetch).
// Output is write-once/never-read: store it with the nt flag so the L3
// stays dedicated to the bf16 operand set.

typedef __bf16 bf16x8 __attribute__((ext_vector_type(8)));
typedef __bf16 bf16x4 __attribute__((ext_vector_type(4)));
typedef float  floatx4 __attribute__((ext_vector_type(4)));

constexpr int Mdim = 8192;
constexpr int Kdim = 4096;
constexpr int Ndim = 11008;
constexpr int NG   = 32;    // groups per output row

__device__ __forceinline__ __bf16 f2b(float f) { return (__bf16)f; }  // fptrunc = RNE

// ---------------------------------------------------------------------------
// Pre-pass 1: x fp32 -> bf16 (grid-stride, float4 in / bf16x4 out)
// ---------------------------------------------------------------------------
__global__ __launch_bounds__(256)
void conv_x_kernel(const float* __restrict__ x, __bf16* __restrict__ xb)
{
    const size_t total4 = (size_t)Mdim * Kdim / 4;
    const size_t stride = (size_t)gridDim.x * blockDim.x;
    for (size_t i = (size_t)blockIdx.x * blockDim.x + threadIdx.x; i < total4; i += stride) {
        const float4 v = ((const float4*)x)[i];
        bf16x4 w;
        w[0] = f2b(v.x); w[1] = f2b(v.y); w[2] = f2b(v.z); w[3] = f2b(v.w);
        ((bf16x4*)xb)[i] = w;
    }
}

// ---------------------------------------------------------------------------
// Pre-pass 2: dequant int32 codes -> bf16 W[N,K]  (w = (q - zero)*scale)
// ---------------------------------------------------------------------------
__global__ __launch_bounds__(256)
void dequant_w_kernel(const int* __restrict__ qw, const float* __restrict__ scales,
                      const float* __restrict__ zeros, __bf16* __restrict__ wb)
{
    const size_t total4 = (size_t)Ndim * Kdim / 4;   // int4 chunks
    const size_t stride = (size_t)gridDim.x * blockDim.x;
    for (size_t i = (size_t)blockIdx.x * blockDim.x + threadIdx.x; i < total4; i += stride) {
        const int n  = (int)(i >> 10);        // / (Kdim/4 = 1024)
        const int k4 = (int)(i & 1023);
        const int g  = k4 >> 5;               // (k4*4) / 128
        const int4 q = ((const int4*)qw)[i];
        const float sf = scales[n * NG + g];
        const float zf = zeros [n * NG + g];
        bf16x4 w;
        w[0] = f2b(((float)q.x - zf) * sf);
        w[1] = f2b(((float)q.y - zf) * sf);
        w[2] = f2b(((float)q.z - zf) * sf);
        w[3] = f2b(((float)q.w - zf) * sf);
        ((bf16x4*)wb)[i] = w;
    }
}

// ---------------------------------------------------------------------------
// Main GEMM: m97 structure. A[M,K] bf16, B[N,K] bf16 (B^T form), out fp32+bias.
// Output stores are NONTEMPORAL (write-once stream; keep L3 for operands).
// ---------------------------------------------------------------------------
#define BM 128
#define BN 128
#define BK 32

typedef const __attribute__((address_space(1))) void* gptr_t;
typedef __attribute__((address_space(3))) void* lptr_t;

__global__ __launch_bounds__(256, 2)
void gemm_bf16(const __bf16* __restrict__ A, const __bf16* __restrict__ Bw,
               const float* __restrict__ bias, float* __restrict__ out)
{
    __shared__ __align__(16) __bf16 sA[BM * BK];   // 8 KB
    __shared__ __align__(16) __bf16 sB[BN * BK];   // 8 KB

    const int n0 = blockIdx.x * BN;
    const int m0 = blockIdx.y * BM;

    const int t    = threadIdx.x;
    const int lane = t & 63;
    const int wave = t >> 6;
    const int wr   = (wave >> 1) * 64;   // wave row origin in tile
    const int wc   = (wave & 1) * 64;    // wave col origin in tile
    const int quad = lane >> 4;
    const int l16  = lane & 15;

    // global_load_lds staging: one wave-issue = 64 lanes x 16B = 1024 B
    // = 16 rows x 64 B (BK=32 bf16). LDS dest is linear: base + lane*16,
    // which matches row = idx*16 + (lane>>2), kbyte = (lane&3)*16 exactly.
    const int srow  = lane >> 2;         // row within 16-row chunk
    const int skoff = (lane & 3) * 8;    // bf16 elem offset within row

    floatx4 acc[4][4] = {};

    const __bf16* Abase = A  + (size_t)m0 * Kdim;
    const __bf16* Bbase = Bw + (size_t)n0 * Kdim;

    for (int k0 = 0; k0 < Kdim; k0 += BK) {
        // ---- stage A & B via async global->LDS (width 16) ----
        #pragma unroll
        for (int p = 0; p < 2; ++p) {
            const int idx = wave * 2 + p;           // 0..7, wave-uniform
            const int row = idx * 16 + srow;
            __builtin_amdgcn_global_load_lds(
                (gptr_t)(Abase + (size_t)row * Kdim + k0 + skoff),
                (lptr_t)(sA + idx * 512), 16, 0, 0);
            __builtin_amdgcn_global_load_lds(
                (gptr_t)(Bbase + (size_t)row * Kdim + k0 + skoff),
                (lptr_t)(sB + idx * 512), 16, 0, 0);
        }
        __syncthreads();   // compiler inserts vmcnt(0) drain before barrier

        // ---- fragments + MFMA: each wave 4x4 of 16x16x32 ----
        bf16x8 af[4], bfr[4];
        #pragma unroll
        for (int i = 0; i < 4; ++i)
            af[i] = *(const bf16x8*)(&sA[(wr + i * 16 + l16) * BK + quad * 8]);
        #pragma unroll
        for (int j = 0; j < 4; ++j)
            bfr[j] = *(const bf16x8*)(&sB[(wc + j * 16 + l16) * BK + quad * 8]);

        #pragma unroll
        for (int i = 0; i < 4; ++i)
            #pragma unroll
            for (int j = 0; j < 4; ++j)
                acc[i][j] = __builtin_amdgcn_mfma_f32_16x16x32_bf16(
                                af[i], bfr[j], acc[i][j], 0, 0, 0);

        __syncthreads();
    }

    // ---- epilogue: C/D layout row=quad*4+r, col=l16; add bias, nt-store ----
    float bj[4];
    #pragma unroll
    for (int j = 0; j < 4; ++j) bj[j] = bias[n0 + wc + j * 16 + l16];

    #pragma unroll
    for (int i = 0; i < 4; ++i) {
        const int m = m0 + wr + i * 16 + quad * 4;
        #pragma unroll
        for (int j = 0; j < 4; ++j) {
            const int n = n0 + wc + j * 16 + l16;
            float* o = out + (size_t)m * Ndim + n;
            #pragma unroll
            for (int r = 0; r < 4; ++r)
                __builtin_nontemporal_store(acc[i][j][r] + bj[j], o + (size_t)r * Ndim);
        }
    }
}

// ---------------------------------------------------------------------------
// Fallback (round-2 verified kernel) if workspace is too small.
// ---------------------------------------------------------------------------
__global__ __launch_bounds__(256, 2)
void qlinear_mfma(const float* __restrict__ x,
                  const int*   __restrict__ qw,
                  const float* __restrict__ scales,
                  const float* __restrict__ zeros,
                  const float* __restrict__ bias,
                  float* __restrict__ out)
{
    __shared__ __align__(16) __bf16 sA[BM * BK];
    __shared__ __align__(16) __bf16 sB[BN * BK];

    const int n0 = blockIdx.x * BN;
    const int m0 = blockIdx.y * BM;

    const int t    = threadIdx.x;
    const int lane = t & 63;
    const int wave = t >> 6;
    const int wr   = (wave >> 1) * 64;
    const int wc   = (wave & 1) * 64;
    const int quad = lane >> 4;
    const int l16  = lane & 15;

    const int sr = t >> 3;
    const int sc = (t & 7) * 4;

    floatx4 acc[4][4] = {};

    for (int k0 = 0; k0 < Kdim; k0 += BK) {
        const int g = k0 >> 7;

        #pragma unroll
        for (int p = 0; p < 4; ++p) {
            const int row = p * 32 + sr;
            const float4 v = *(const float4*)(x + (m0 + row) * Kdim + k0 + sc);
            bf16x4 w;
            w[0] = f2b(v.x); w[1] = f2b(v.y); w[2] = f2b(v.z); w[3] = f2b(v.w);
            *(bf16x4*)(&sA[row * BK + sc]) = w;
        }
        #pragma unroll
        for (int p = 0; p < 4; ++p) {
            const int row = p * 32 + sr;
            const int n   = n0 + row;
            const int4 q  = *(const int4*)(qw + n * Kdim + k0 + sc);
            const float sf = scales[n * NG + g];
            const float zf = zeros [n * NG + g];
            bf16x4 w;
            w[0] = f2b(((float)q.x - zf) * sf);
            w[1] = f2b(((float)q.y - zf) * sf);
            w[2] = f2b(((float)q.z - zf) * sf);
            w[3] = f2b(((float)q.w - zf) * sf);
            *(bf16x4*)(&sB[row * BK + sc]) = w;
        }
        __syncthreads();

        bf16x8 af[4], bfr[4];
        #pragma unroll
        for (int i = 0; i < 4; ++i)
            af[i] = *(bf16x8*)(&sA[(wr + i * 16 + l16) * BK + quad * 8]);
        #pragma unroll
        for (int j = 0; j < 4; ++j)
            bfr[j] = *(bf16x8*)(&sB[(wc + j * 16 + l16) * BK + quad * 8]);

        #pragma unroll
        for (int i = 0; i < 4; ++i)
            #pragma unroll
            for (int j = 0; j < 4; ++j)
                acc[i][j] = __builtin_amdgcn_mfma_f32_16x16x32_bf16(
                                af[i], bfr[j], acc[i][j], 0, 0, 0);

        __syncthreads();
    }

    float bj[4];
    #pragma unroll
    for (int j = 0; j < 4; ++j) bj[j] = bias[n0 + wc + j * 16 + l16];

    #pragma unroll
    for (int i = 0; i < 4; ++i) {
        const int m = m0 + wr + i * 16 + quad * 4;
        #pragma unroll
        for (int j = 0; j < 4; ++j) {
            const int n = n0 + wc + j * 16 + l16;
            float* o = out + (size_t)m * Ndim + n;
            #pragma unroll
            for (int r = 0; r < 4; ++r)
                o[(size_t)r * Ndim] = acc[i][j][r] + bj[j];
        }
    }
}

extern "C" void kernel_launch(void* const* d_in, const int* in_sizes, int n_in,
                              void* d_out, int out_size, void* d_ws, size_t ws_size,
                              hipStream_t stream) {
    const float* x      = (const float*)d_in[0];
    const int*   qwt    = (const int*)d_in[1];
    const float* scales = (const float*)d_in[2];
    const float* zeros  = (const float*)d_in[3];
    const float* bias   = (const float*)d_in[4];
    float* out = (float*)d_out;

    const size_t xb_bytes = (size_t)Mdim * Kdim * sizeof(__bf16);   // 64 MiB
    const size_t wb_bytes = (size_t)Ndim * Kdim * sizeof(__bf16);   // ~86 MiB
    const size_t needed   = xb_bytes + wb_bytes;                    // 150 MiB

    if (ws_size >= needed && d_ws != nullptr) {
        __bf16* xb = (__bf16*)d_ws;
        __bf16* wb = (__bf16*)((char*)d_ws + xb_bytes);

        conv_x_kernel  <<<2048, 256, 0, stream>>>(x, xb);
        dequant_w_kernel<<<2048, 256, 0, stream>>>(qwt, scales, zeros, wb);

        dim3 grid(Ndim / BN, Mdim / BM);   // 86 x 64 = 5504 blocks
        gemm_bf16<<<grid, 256, 0, stream>>>(xb, wb, bias, out);
    } else {
        dim3 grid(Ndim / BN, Mdim / BM);
        qlinear_mfma<<<grid, 256, 0, stream>>>(x, qwt, scales, zeros, bias, out);
    }
}